// Round 11
// baseline (206.607 us; speedup 1.0000x reference)
//
#include <hip/hip_runtime.h>
#include <hip/hip_bf16.h>

#define C_ 10
#define B_ 8192
#define F_ 256
#define O_ 64
#define DK_ 5
#define NPROD 256   // producer tickets (32 rows each)
#define NSPEC 160   // special tickets (WTB convert + G2 fan-in)
#define NBLK  1280

typedef __attribute__((ext_vector_type(8))) short short8;
typedef __attribute__((ext_vector_type(4))) float floatx4;

static __device__ __forceinline__ unsigned short f2bf(float f) {
    union { float f; unsigned u; } v; v.f = f;
    unsigned r = v.u + 0x7fffu + ((v.u >> 16) & 1u);  // round-nearest-even
    return (unsigned short)(r >> 16);
}

// Single fused kernel. Role by arrival ticket (resident blocks become
// producers -> no dispatch-order assumption). Flags are >= monotonic with
// bounded spins: no input state can hang; counters memset to 0 each call.
__global__ __launch_bounds__(256) void mega(const float* __restrict__ x,
                                            const float* __restrict__ y,
                                            const float* __restrict__ w_key,
                                            const float* __restrict__ w_query,
                                            const float* __restrict__ w_value,
                                            const float* __restrict__ weight,
                                            const float* __restrict__ bias,
                                            float* __restrict__ G_part,
                                            float* __restrict__ G2,
                                            unsigned short* __restrict__ WTB,
                                            unsigned int* __restrict__ cnt,
                                            float* __restrict__ out) {
    __shared__ union {
        struct { float xl[32 * F_]; float yl[32 * C_]; } p;                       // phase A
        struct { unsigned short wt[O_ * F_]; float a2s[F_]; float wred[4]; } g;   // phase C
    } sh;
    __shared__ unsigned int tk;

    const int t   = threadIdx.x;
    const int blk = blockIdx.x;

    if (t == 0) tk = __hip_atomic_fetch_add(&cnt[0], 1u, __ATOMIC_RELAXED,
                                            __HIP_MEMORY_SCOPE_AGENT);
    __syncthreads();
    const unsigned int ticket = tk;

    if (ticket < NPROD) {
        // ---------- Phase A: G_part[ticket][c][f] over rows [32t, 32t+32) ----
        const int pb0 = (int)ticket * 32;
        for (int i = t; i < 32 * C_; i += 256) sh.p.yl[i] = y[pb0 * C_ + i];
        const int r  = t >> 6;
        const int f4 = (t & 63) * 4;
#pragma unroll
        for (int j = 0; j < 8; ++j) {
            int row = r + 4 * j;
            *(float4*)(sh.p.xl + row * F_ + f4) =
                *(const float4*)(x + (size_t)(pb0 + row) * F_ + f4);
        }
        __syncthreads();
        float acc[C_];
#pragma unroll
        for (int c = 0; c < C_; ++c) acc[c] = 0.f;
#pragma unroll 8
        for (int b = 0; b < 32; ++b) {
            float xv = sh.p.xl[b * F_ + t];
#pragma unroll
            for (int c = 0; c < C_; ++c) acc[c] = fmaf(sh.p.yl[b * C_ + c], xv, acc[c]);
        }
        float* gp = G_part + (size_t)ticket * C_ * F_ + t;
#pragma unroll
        for (int c = 0; c < C_; ++c) gp[c * F_] = acc[c];
        __threadfence();
        __syncthreads();      // all stores drained (vmcnt0) before release
        if (t == 0) __hip_atomic_fetch_add(&cnt[16], 1u, __ATOMIC_RELEASE,
                                           __HIP_MEMORY_SCOPE_AGENT);
    } else if (ticket < NPROD + NSPEC) {
        // ---------- specials: WTB convert (static) then G2 fan-in ----------
        const int sp = (int)ticket - NPROD;   // 0..159
        const int cc = sp >> 4, g = sp & 15;
        {   // weight -> bf16, swizzle-baked: byte(o,f) = o*512 + ((2f)^((o&7)<<4))
            const int o  = t & 63;
            const int fq = t >> 6;
            const int f0 = g * 16 + fq * 4;
            const float* wsrc = weight + (size_t)cc * F_ * O_;
            ushort4 v;
            v.x = f2bf(wsrc[(f0 + 0) * O_ + o]);
            v.y = f2bf(wsrc[(f0 + 1) * O_ + o]);
            v.z = f2bf(wsrc[(f0 + 2) * O_ + o]);
            v.w = f2bf(wsrc[(f0 + 3) * O_ + o]);
            *(ushort4*)((char*)(WTB + (size_t)cc * O_ * F_)
                        + o * 512 + ((2 * f0) ^ ((o & 7) << 4))) = v;
        }
        if (t == 0) {
            int gd = 0;
            while (__hip_atomic_load(&cnt[16], __ATOMIC_ACQUIRE,
                                     __HIP_MEMORY_SCOPE_AGENT) < NPROD
                   && gd < (1 << 16)) { __builtin_amdgcn_s_sleep(16); ++gd; }
        }
        __syncthreads();
        const float* gp = G_part + (size_t)(g * 16) * C_ * F_ + cc * F_ + t;
        float a0 = 0.f, a1 = 0.f, a2 = 0.f, a3 = 0.f;
#pragma unroll
        for (int i = 0; i < 16; i += 4) {
            a0 += gp[(size_t)(i + 0) * C_ * F_];
            a1 += gp[(size_t)(i + 1) * C_ * F_];
            a2 += gp[(size_t)(i + 2) * C_ * F_];
            a3 += gp[(size_t)(i + 3) * C_ * F_];
        }
        G2[(size_t)g * C_ * F_ + cc * F_ + t] = (a0 + a1) + (a2 + a3);
        __threadfence();
        __syncthreads();
        if (t == 0) __hip_atomic_fetch_add(&cnt[32], 1u, __ATOMIC_RELEASE,
                                           __HIP_MEMORY_SCOPE_AGENT);
    }

    // ---------- Phase C identity + x prefetch (issues before the spin) ------
    const int c  = blk >> 7;           // 0..9
    const int b0 = (blk & 127) * 64;
    const int w  = t >> 6;
    const int l  = t & 63;
    const int lr = l & 15;
    const int lg = l >> 4;

    const float* xr = x + (size_t)(b0 + w * 16 + lr) * F_;
    float4 araw0[8], araw1[8];
#pragma unroll
    for (int k0 = 0; k0 < 8; ++k0) {
        araw0[k0] = *(const float4*)(xr + k0 * 32 + lg * 8);
        araw1[k0] = *(const float4*)(xr + k0 * 32 + lg * 8 + 4);
    }
    const float bo0 = bias[c * O_ + lr];
    const float bo1 = bias[c * O_ + 16 + lr];
    const float bo2 = bias[c * O_ + 32 + lr];
    const float bo3 = bias[c * O_ + 48 + lr];

    if (t == 0) {
        int gd = 0;
        while (__hip_atomic_load(&cnt[32], __ATOMIC_ACQUIRE,
                                 __HIP_MEMORY_SCOPE_AGENT) < NSPEC
               && gd < (1 << 16)) { __builtin_amdgcn_s_sleep(32); ++gd; }
    }
    __syncthreads();

    // ---------- stage WTB[c] -> LDS (linear; swizzle pre-baked) ------------
    {
        const short8* src = (const short8*)(WTB + (size_t)c * O_ * F_);
        short8* dst = (short8*)sh.g.wt;
#pragma unroll
        for (int j = 0; j < 8; ++j) dst[t + 256 * j] = src[t + 256 * j];
    }
    // ---------- G2 reduce + softmax -> a2s ---------------------------------
    {
        const float* gp = G2 + c * F_ + t;
        float g0 = 0.f, g1 = 0.f, g2 = 0.f, g3 = 0.f;
#pragma unroll
        for (int i = 0; i < 16; i += 4) {
            g0 += gp[(size_t)(i + 0) * C_ * F_];
            g1 += gp[(size_t)(i + 1) * C_ * F_];
            g2 += gp[(size_t)(i + 2) * C_ * F_];
            g3 += gp[(size_t)(i + 3) * C_ * F_];
        }
        float g = (g0 + g1) + (g2 + g3);

        float s = 0.f;
#pragma unroll
        for (int k = 0; k < DK_; ++k) s += w_key[c * DK_ + k] * w_query[c * DK_ + k];

        float z = s * g * (1.0f / (float)B_);
        float m = z;
#pragma unroll
        for (int off = 32; off >= 1; off >>= 1) m = fmaxf(m, __shfl_xor(m, off));
        if ((t & 63) == 0) sh.g.wred[t >> 6] = m;
        __syncthreads();
        float mm = fmaxf(fmaxf(sh.g.wred[0], sh.g.wred[1]),
                         fmaxf(sh.g.wred[2], sh.g.wred[3]));
        sh.g.a2s[t] = expf(z - mm) * w_value[c];
    }
    __syncthreads();   // wt staged + a2s ready

    // ---------- A-scale in registers: afr = bf16(x * a2) -------------------
    short8 afr[8];
#pragma unroll
    for (int k0 = 0; k0 < 8; ++k0) {
        const int kk = k0 * 32 + lg * 8;
        float4 s0 = *(const float4*)(sh.g.a2s + kk);
        float4 s1 = *(const float4*)(sh.g.a2s + kk + 4);
        short8 fr;
        fr[0] = (short)f2bf(araw0[k0].x * s0.x);
        fr[1] = (short)f2bf(araw0[k0].y * s0.y);
        fr[2] = (short)f2bf(araw0[k0].z * s0.z);
        fr[3] = (short)f2bf(araw0[k0].w * s0.w);
        fr[4] = (short)f2bf(araw1[k0].x * s1.x);
        fr[5] = (short)f2bf(araw1[k0].y * s1.y);
        fr[6] = (short)f2bf(araw1[k0].z * s1.z);
        fr[7] = (short)f2bf(araw1[k0].w * s1.w);
        afr[k0] = fr;
    }

    floatx4 acc[4];
    acc[0] = (floatx4){bo0, bo0, bo0, bo0};
    acc[1] = (floatx4){bo1, bo1, bo1, bo1};
    acc[2] = (floatx4){bo2, bo2, bo2, bo2};
    acc[3] = (floatx4){bo3, bo3, bo3, bo3};

#pragma unroll
    for (int k0 = 0; k0 < 8; ++k0) {
#pragma unroll
        for (int n = 0; n < 4; ++n) {
            int o = n * 16 + lr;
            int byte = o * 512 + ((k0 * 64 + lg * 16) ^ ((o & 7) << 4));
            short8 bf = *(const short8*)((const char*)sh.g.wt + byte);
            acc[n] = __builtin_amdgcn_mfma_f32_16x16x32_bf16(afr[k0], bf, acc[n], 0, 0, 0);
        }
    }

    // D layout: col = lane&15, row = (lane>>4)*4 + reg
#pragma unroll
    for (int n = 0; n < 4; ++n) {
        int col = n * 16 + lr;
#pragma unroll
        for (int r2 = 0; r2 < 4; ++r2) {
            int row = b0 + w * 16 + lg * 4 + r2;
            out[((size_t)c * B_ + row) * O_ + col] = acc[n][r2];
        }
    }
}

extern "C" void kernel_launch(void* const* d_in, const int* in_sizes, int n_in,
                              void* d_out, int out_size, void* d_ws, size_t ws_size,
                              hipStream_t stream) {
    const float* x       = (const float*)d_in[0];
    const float* y       = (const float*)d_in[1];
    const float* w_key   = (const float*)d_in[2];
    const float* w_query = (const float*)d_in[3];
    const float* w_value = (const float*)d_in[4];
    const float* weight  = (const float*)d_in[5];
    const float* bias    = (const float*)d_in[6];
    float* out = (float*)d_out;

    char* ws = (char*)d_ws;
    float*          G_part = (float*)ws;                                    // 2.62 MiB
    float*          G2     = G_part + (size_t)NPROD * C_ * F_;              // 160 KiB
    unsigned short* WTB    = (unsigned short*)(G2 + (size_t)16 * C_ * F_);  // 320 KiB
    unsigned int*   cnt    = (unsigned int*)(WTB + (size_t)C_ * O_ * F_);   // 192 B

    hipMemsetAsync(cnt, 0, 192, stream);   // ticket + flag1 + flag2 (poison-proof)
    mega<<<NBLK, 256, 0, stream>>>(x, y, w_key, w_query, w_value, weight, bias,
                                   G_part, G2, WTB, cnt, out);
}

// Round 12
// 32.875 us; speedup vs baseline: 6.2846x; 6.2846x over previous
//
#include <hip/hip_runtime.h>
#include <hip/hip_bf16.h>

#define C_ 10
#define B_ 8192
#define F_ 256
#define O_ 64
#define DK_ 5
#define P_ 64      // G partial count (128 rows each)

typedef __attribute__((ext_vector_type(8))) short short8;
typedef __attribute__((ext_vector_type(4))) float floatx4;

static __device__ __forceinline__ unsigned short f2bf(float f) {
    union { float f; unsigned u; } v; v.f = f;
    unsigned r = v.u + 0x7fffu + ((v.u >> 16) & 1u);  // round-nearest-even
    return (unsigned short)(r >> 16);
}

// ---------------- K_A: G partials (blocks 0..63) + weight convert (64..103) -
__global__ __launch_bounds__(256) void kA(const float* __restrict__ x,
                                          const float* __restrict__ y,
                                          const float* __restrict__ weight,
                                          float* __restrict__ G_part,
                                          unsigned short* __restrict__ WTB) {
    const int t = threadIdx.x;
    if (blockIdx.x < P_) {
        // G_part[blk][c][f] = sum over 128 rows of x[b,f]*y[b,c]
        __shared__ float yl[128 * C_];     // 5 KiB
        const int b0 = blockIdx.x * 128;
        for (int i = t; i < 128 * C_; i += 256) yl[i] = y[b0 * C_ + i];
        __syncthreads();

        float acc[C_];
#pragma unroll
        for (int c = 0; c < C_; ++c) acc[c] = 0.f;

        const float* xp = x + (size_t)b0 * F_ + t;   // lane-consecutive: coalesced
#pragma unroll 8
        for (int b = 0; b < 128; ++b) {
            float xv = xp[(size_t)b * F_];
#pragma unroll
            for (int c = 0; c < C_; ++c) acc[c] = fmaf(yl[b * C_ + c], xv, acc[c]);
        }

        float* gp = G_part + (size_t)blockIdx.x * C_ * F_ + t;
#pragma unroll
        for (int c = 0; c < C_; ++c) gp[c * F_] = acc[c];   // coalesced
    } else {
        // weight[c][f][o] -> WTB[c] bf16, swizzle-baked:
        // byte(o,f) = o*512 + ((2f) ^ ((o&7)<<4)); block (cc, part=64-f-rows)
        const int sp   = (int)blockIdx.x - P_;   // 0..39
        const int cc   = sp >> 2;
        const int part = sp & 3;
        const int o  = t & 63;
        const int fq = t >> 6;
        const float* wsrc = weight + (size_t)cc * F_ * O_;
        char* wb = (char*)(WTB + (size_t)cc * O_ * F_);
#pragma unroll
        for (int gi = 0; gi < 4; ++gi) {
            int f0 = part * 64 + gi * 16 + fq * 4;
            ushort4 v;
            v.x = f2bf(wsrc[(f0 + 0) * O_ + o]);   // lanes o -> coalesced 256B
            v.y = f2bf(wsrc[(f0 + 1) * O_ + o]);
            v.z = f2bf(wsrc[(f0 + 2) * O_ + o]);
            v.w = f2bf(wsrc[(f0 + 3) * O_ + o]);
            *(ushort4*)(wb + o * 512 + ((2 * f0) ^ ((o & 7) << 4))) = v;  // 8B aligned
        }
    }
}

// ---------------- K_B: fan-in + softmax + A-scale + MFMA GEMM ---------------
// grid (128 tiles, 10 c). Per block: wave-parallel 16-deep fan-in of G_part,
// softmax -> a2s, stage WTB[c] (pre-swizzled), scale A in regs to bf16, MFMA.
__global__ __launch_bounds__(256) void kB(const float* __restrict__ x,
                                          const float* __restrict__ G_part,
                                          const float* __restrict__ w_key,
                                          const float* __restrict__ w_query,
                                          const float* __restrict__ w_value,
                                          const float* __restrict__ bias,
                                          const unsigned short* __restrict__ WTB,
                                          float* __restrict__ out) {
    __shared__ unsigned short wt[O_ * F_];  // 32 KiB swizzled [o][k]
    __shared__ float red[4 * F_];           // 4 KiB wave partials
    __shared__ float a2s[F_];
    __shared__ float wred[4];
    const int c  = blockIdx.y;
    const int b0 = blockIdx.x * 64;
    const int t  = threadIdx.x;
    const int w  = t >> 6;
    const int l  = t & 63;
    const int lr = l & 15;
    const int lg = l >> 4;

    // 1) x prefetch FIRST (f32, L3-hot): overlaps everything below
    const float* xr = x + (size_t)(b0 + w * 16 + lr) * F_;
    float4 araw0[8], araw1[8];
#pragma unroll
    for (int k0 = 0; k0 < 8; ++k0) {
        araw0[k0] = *(const float4*)(xr + k0 * 32 + lg * 8);
        araw1[k0] = *(const float4*)(xr + k0 * 32 + lg * 8 + 4);
    }
    const float bo0 = bias[c * O_ + lr];
    const float bo1 = bias[c * O_ + 16 + lr];
    const float bo2 = bias[c * O_ + 32 + lr];
    const float bo3 = bias[c * O_ + 48 + lr];

    // 2) wave-parallel fan-in: wave pg sums partials [pg*16, pg*16+16)
    //    for features l+{0,64,128,192} (coalesced 256B rows, independent)
    {
        const float* gp = G_part + ((size_t)(w * 16) * C_ + c) * F_ + l;
        float s0 = 0.f, s1 = 0.f, s2 = 0.f, s3 = 0.f;
#pragma unroll
        for (int p = 0; p < 16; ++p) {
            const float* q = gp + (size_t)p * C_ * F_;
            s0 += q[0]; s1 += q[64]; s2 += q[128]; s3 += q[192];
        }
        red[w * F_ + l]       = s0;
        red[w * F_ + 64 + l]  = s1;
        red[w * F_ + 128 + l] = s2;
        red[w * F_ + 192 + l] = s3;
    }

    // 3) stage WTB[c] -> LDS linearly (swizzle pre-baked, L2/L3-hot)
    {
        const short8* src = (const short8*)(WTB + (size_t)c * O_ * F_);
        short8* dst = (short8*)wt;
#pragma unroll
        for (int j = 0; j < 8; ++j) dst[t + 256 * j] = src[t + 256 * j];
    }
    __syncthreads();   // red + wt complete

    // 4) combine + softmax -> a2s
    {
        float g = (red[t] + red[F_ + t]) + (red[2 * F_ + t] + red[3 * F_ + t]);

        float s = 0.f;
#pragma unroll
        for (int k = 0; k < DK_; ++k) s += w_key[c * DK_ + k] * w_query[c * DK_ + k];

        float z = s * g * (1.0f / (float)B_);
        float m = z;
#pragma unroll
        for (int off = 32; off >= 1; off >>= 1) m = fmaxf(m, __shfl_xor(m, off));
        if ((t & 63) == 0) wred[t >> 6] = m;
        __syncthreads();
        float mm = fmaxf(fmaxf(wred[0], wred[1]), fmaxf(wred[2], wred[3]));
        a2s[t] = expf(z - mm) * w_value[c];
    }
    __syncthreads();

    // 5) A-scale in registers: afr = bf16(x * a2)
    short8 afr[8];
#pragma unroll
    for (int k0 = 0; k0 < 8; ++k0) {
        const int kk = k0 * 32 + lg * 8;
        float4 s0 = *(const float4*)(a2s + kk);
        float4 s1 = *(const float4*)(a2s + kk + 4);
        short8 fr;
        fr[0] = (short)f2bf(araw0[k0].x * s0.x);
        fr[1] = (short)f2bf(araw0[k0].y * s0.y);
        fr[2] = (short)f2bf(araw0[k0].z * s0.z);
        fr[3] = (short)f2bf(araw0[k0].w * s0.w);
        fr[4] = (short)f2bf(araw1[k0].x * s1.x);
        fr[5] = (short)f2bf(araw1[k0].y * s1.y);
        fr[6] = (short)f2bf(araw1[k0].z * s1.z);
        fr[7] = (short)f2bf(araw1[k0].w * s1.w);
        afr[k0] = fr;
    }

    floatx4 acc[4];
    acc[0] = (floatx4){bo0, bo0, bo0, bo0};
    acc[1] = (floatx4){bo1, bo1, bo1, bo1};
    acc[2] = (floatx4){bo2, bo2, bo2, bo2};
    acc[3] = (floatx4){bo3, bo3, bo3, bo3};

#pragma unroll
    for (int k0 = 0; k0 < 8; ++k0) {
#pragma unroll
        for (int n = 0; n < 4; ++n) {
            int o = n * 16 + lr;
            int byte = o * 512 + ((k0 * 64 + lg * 16) ^ ((o & 7) << 4));
            short8 bf = *(const short8*)((const char*)wt + byte);  // conflict-free
            acc[n] = __builtin_amdgcn_mfma_f32_16x16x32_bf16(afr[k0], bf, acc[n], 0, 0, 0);
        }
    }

    // D layout: col = lane&15, row = (lane>>4)*4 + reg
#pragma unroll
    for (int n = 0; n < 4; ++n) {
        int col = n * 16 + lr;
#pragma unroll
        for (int r2 = 0; r2 < 4; ++r2) {
            int row = b0 + w * 16 + lg * 4 + r2;
            out[((size_t)c * B_ + row) * O_ + col] = acc[n][r2];
        }
    }
}

extern "C" void kernel_launch(void* const* d_in, const int* in_sizes, int n_in,
                              void* d_out, int out_size, void* d_ws, size_t ws_size,
                              hipStream_t stream) {
    const float* x       = (const float*)d_in[0];
    const float* y       = (const float*)d_in[1];
    const float* w_key   = (const float*)d_in[2];
    const float* w_query = (const float*)d_in[3];
    const float* w_value = (const float*)d_in[4];
    const float* weight  = (const float*)d_in[5];
    const float* bias    = (const float*)d_in[6];
    float* out = (float*)d_out;

    char* ws = (char*)d_ws;
    float*          G_part = (float*)ws;                                 // 640 KiB
    unsigned short* WTB    = (unsigned short*)(G_part + (size_t)P_ * C_ * F_);  // 320 KiB

    kA<<<P_ + C_ * 4, 256, 0, stream>>>(x, y, weight, G_part, WTB);
    dim3 g(B_ / 64, C_);
    kB<<<g, 256, 0, stream>>>(x, G_part, w_key, w_query, w_value, bias, WTB, out);
}

// Round 13
// 28.041 us; speedup vs baseline: 7.3681x; 1.1724x over previous
//
#include <hip/hip_runtime.h>
#include <hip/hip_bf16.h>

#define C_ 10
#define B_ 8192
#define F_ 256
#define O_ 64
#define DK_ 5
#define NBLK1 256   // k1 blocks -> partial count
#define NG2   16    // second-level partial count

typedef __attribute__((ext_vector_type(8))) short short8;
typedef __attribute__((ext_vector_type(4))) float floatx4;

static __device__ __forceinline__ unsigned short f2bf(float f) {
    union { float f; unsigned u; } v; v.f = f;
    unsigned r = v.u + 0x7fffu + ((v.u >> 16) & 1u);  // round-nearest-even
    return (unsigned short)(r >> 16);
}

// ---------------- K1: per-block partial G + emit x as bf16 ------------------
// G_part[blk][c][f] = sum_{b in block} x[b,f]*y[b,c]   (no atomics, no memset)
__global__ __launch_bounds__(256) void k1_reduce(const float* __restrict__ x,
                                                 const float* __restrict__ y,
                                                 float* __restrict__ G_part,
                                                 unsigned short* __restrict__ xb) {
    __shared__ float xl[32 * F_];      // 32 KiB
    __shared__ float yl[32 * C_];
    const int b0 = blockIdx.x * 32;
    const int t  = threadIdx.x;

    for (int i = t; i < 32 * C_; i += 256) yl[i] = y[b0 * C_ + i];

    const int r  = t >> 6;             // row sub-slot 0..3
    const int f4 = (t & 63) * 4;       // 4 features per thread
#pragma unroll
    for (int j = 0; j < 8; ++j) {
        int row = r + 4 * j;           // 0..31
        float4 v = *(const float4*)(x + (size_t)(b0 + row) * F_ + f4);
        *(float4*)(xl + row * F_ + f4) = v;
        ushort4 s;
        s.x = f2bf(v.x); s.y = f2bf(v.y); s.z = f2bf(v.z); s.w = f2bf(v.w);
        *(ushort4*)(xb + (size_t)(b0 + row) * F_ + f4) = s;
    }
    __syncthreads();

    float acc[C_];
#pragma unroll
    for (int c = 0; c < C_; ++c) acc[c] = 0.f;

#pragma unroll 8
    for (int b = 0; b < 32; ++b) {
        float xv = xl[b * F_ + t];     // 2-way bank alias (free)
#pragma unroll
        for (int c = 0; c < C_; ++c) acc[c] = fmaf(yl[b * C_ + c], xv, acc[c]);
    }

    float* gp = G_part + (size_t)blockIdx.x * C_ * F_ + t;
#pragma unroll
    for (int c = 0; c < C_; ++c) gp[c * F_] = acc[c];   // coalesced, non-atomic
}

// ---------------- K1b: tree fan-in, 16 partials per block, coalesced --------
// G2[g][c][f] = sum_{i<16} G_part[g*16+i][c][f];  grid = C_*NG2 = 160 blocks
__global__ __launch_bounds__(256) void k1b_reduce(const float* __restrict__ G_part,
                                                  float* __restrict__ G2) {
    const int c = (int)blockIdx.x >> 4;
    const int g = (int)blockIdx.x & 15;
    const int t = threadIdx.x;
    const float* gp = G_part + (size_t)(g * 16) * C_ * F_ + c * F_ + t;
    float a0 = 0.f, a1 = 0.f, a2 = 0.f, a3 = 0.f;
#pragma unroll
    for (int i = 0; i < 16; i += 4) {   // 16 independent coalesced 1KB-row loads
        a0 += gp[(size_t)(i + 0) * C_ * F_];
        a1 += gp[(size_t)(i + 1) * C_ * F_];
        a2 += gp[(size_t)(i + 2) * C_ * F_];
        a3 += gp[(size_t)(i + 3) * C_ * F_];
    }
    G2[(size_t)g * C_ * F_ + c * F_ + t] = (a0 + a1) + (a2 + a3);
}

// ---------------- K2: final reduce + softmax + weight prep. 4 blocks per c --
// attn2[f] = exp(z-zmax)*w_value[c] (redundant per block);
// WT[c] swizzle-baked bf16 [o][k=f]: byte(o,f) = o*512 + ((2f) ^ ((o&7)<<4))
__global__ __launch_bounds__(256) void k2_wprep(const float* __restrict__ G2,
                                                const float* __restrict__ w_key,
                                                const float* __restrict__ w_query,
                                                const float* __restrict__ w_value,
                                                const float* __restrict__ weight,
                                                unsigned short* __restrict__ WT) {
    __shared__ float a2[F_];
    __shared__ float wred[4];
    const int c    = blockIdx.x >> 2;
    const int part = blockIdx.x & 3;   // 64 features each for the prep phase
    const int t    = threadIdx.x;

    // sum the 16 second-level partials for (c, f=t): coalesced, fully parallel
    const float* gp = G2 + c * F_ + t;
    float g0 = 0.f, g1 = 0.f, g2 = 0.f, g3 = 0.f;
#pragma unroll
    for (int i = 0; i < NG2; i += 4) {
        g0 += gp[(size_t)(i + 0) * C_ * F_];
        g1 += gp[(size_t)(i + 1) * C_ * F_];
        g2 += gp[(size_t)(i + 2) * C_ * F_];
        g3 += gp[(size_t)(i + 3) * C_ * F_];
    }
    float g = (g0 + g1) + (g2 + g3);

    float s = 0.f;
#pragma unroll
    for (int k = 0; k < DK_; ++k) s += w_key[c * DK_ + k] * w_query[c * DK_ + k];

    float z = s * g * (1.0f / (float)B_);
    float m = z;
#pragma unroll
    for (int off = 32; off >= 1; off >>= 1) m = fmaxf(m, __shfl_xor(m, off));
    if ((t & 63) == 0) wred[t >> 6] = m;
    __syncthreads();
    float mm = fmaxf(fmaxf(wred[0], wred[1]), fmaxf(wred[2], wred[3]));
    a2[t] = expf(z - mm) * w_value[c];
    __syncthreads();

    const int o  = t & 63;
    const int fg = t >> 6;
    const float* wsrc = weight + (size_t)c * F_ * O_;
    char* wdst = (char*)(WT + (size_t)c * O_ * F_);
#pragma unroll
    for (int gi = 0; gi < 2; ++gi) {
        int f0 = part * 64 + fg * 16 + gi * 8;
        short8 v8;
#pragma unroll
        for (int e = 0; e < 8; ++e) {
            int f = f0 + e;
            v8[e] = (short)f2bf(wsrc[f * O_ + o] * a2[f]);  // coalesced along o
        }
        int byte = o * 512 + ((2 * f0) ^ ((o & 7) << 4));   // 16B-aligned
        *(short8*)(wdst + byte) = v8;
    }
}

// ---------------- K3: two c's per block; A-frags loaded once ----------------
// grid (128 tiles, 5 c-pairs). Stage WT[c0]||WT[c1] (64 KiB, one linear copy),
// prefetch A-frags (c-independent), then two 64-MFMA passes + stores.
__global__ __launch_bounds__(256) void k3_mfma(const unsigned short* __restrict__ xb,
                                               const unsigned short* __restrict__ WT,
                                               const float* __restrict__ bias,
                                               float* __restrict__ out) {
    __shared__ unsigned short wt2[2 * O_ * F_];  // 64 KiB swizzled [c-half][o][k]
    const int cp = blockIdx.y;        // c-pair 0..4 -> c = 2*cp, 2*cp+1
    const int b0 = blockIdx.x * 64;
    const int t  = threadIdx.x;
    const int w  = t >> 6;
    const int l  = t & 63;
    const int lr = l & 15;
    const int lg = l >> 4;

    // A prefetch: 8 x short8 (row b0+w*16+lr, k = k0*32 + lg*8), issues early
    const unsigned short* xrow = xb + (size_t)(b0 + w * 16 + lr) * F_;
    short8 a[8];
#pragma unroll
    for (int k0 = 0; k0 < 8; ++k0) a[k0] = *(const short8*)(xrow + k0 * 32 + lg * 8);

    // stage WT[2cp] and WT[2cp+1] linearly (swizzle pre-baked): 64 KiB
    {
        const short8* src = (const short8*)(WT + (size_t)(2 * cp) * O_ * F_);
        short8* dst = (short8*)wt2;
#pragma unroll
        for (int j = 0; j < 16; ++j) dst[t + 256 * j] = src[t + 256 * j];
    }
    __syncthreads();

#pragma unroll
    for (int half = 0; half < 2; ++half) {
        const int c = 2 * cp + half;
        const char* wbase = (const char*)wt2 + half * (O_ * F_ * 2);

        floatx4 acc[4];
#pragma unroll
        for (int n = 0; n < 4; ++n) {
            float bo = bias[c * O_ + n * 16 + lr];
            acc[n] = (floatx4){bo, bo, bo, bo};   // bias folded into C-init
        }

#pragma unroll
        for (int k0 = 0; k0 < 8; ++k0) {
#pragma unroll
            for (int n = 0; n < 4; ++n) {
                int o = n * 16 + lr;
                int byte = o * 512 + ((k0 * 64 + lg * 16) ^ ((o & 7) << 4));
                short8 bf = *(const short8*)(wbase + byte);  // conflict-free
                acc[n] = __builtin_amdgcn_mfma_f32_16x16x32_bf16(a[k0], bf, acc[n], 0, 0, 0);
            }
        }

        // D layout: col = lane&15, row = (lane>>4)*4 + reg
#pragma unroll
        for (int n = 0; n < 4; ++n) {
            int col = n * 16 + lr;
#pragma unroll
            for (int r = 0; r < 4; ++r) {
                int row = b0 + w * 16 + lg * 4 + r;
                out[((size_t)c * B_ + row) * O_ + col] = acc[n][r];
            }
        }
    }
}

extern "C" void kernel_launch(void* const* d_in, const int* in_sizes, int n_in,
                              void* d_out, int out_size, void* d_ws, size_t ws_size,
                              hipStream_t stream) {
    const float* x       = (const float*)d_in[0];
    const float* y       = (const float*)d_in[1];
    const float* w_key   = (const float*)d_in[2];
    const float* w_query = (const float*)d_in[3];
    const float* w_value = (const float*)d_in[4];
    const float* weight  = (const float*)d_in[5];
    const float* bias    = (const float*)d_in[6];
    float* out = (float*)d_out;

    char* ws = (char*)d_ws;
    unsigned short* xb     = (unsigned short*)ws;                                  // 4 MiB
    unsigned short* WT     = (unsigned short*)(ws + (size_t)B_ * F_ * 2);          // 320 KiB
    float*          G_part = (float*)(ws + (size_t)B_ * F_ * 2 + C_ * O_ * F_ * 2);// 2.62 MiB
    float*          G2     = G_part + (size_t)NBLK1 * C_ * F_;                     // 160 KiB

    k1_reduce<<<NBLK1, 256, 0, stream>>>(x, y, G_part, xb);
    k1b_reduce<<<C_ * NG2, 256, 0, stream>>>(G_part, G2);
    k2_wprep<<<C_ * 4, 256, 0, stream>>>(G2, w_key, w_query, w_value, weight, WT);
    dim3 g3(B_ / 64, C_ / 2);
    k3_mfma<<<g3, 256, 0, stream>>>(xb, WT, bias, out);
}